// Round 11
// baseline (60.414 us; speedup 1.0000x reference)
//
#include <hip/hip_runtime.h>

constexpr int B   = 1024;
constexpr int T   = 8192;
constexpr int MS  = 128;
constexpr int NF4 = T / 2;     // 4096 2-t prefix entries per row

// Padded LDS index for prefix entry k (k in [0, 4096]): idx = k + (k>>4).
// For k = 16*tid + j (j<16) this is 17*tid + j.
__device__ __forceinline__ int pidx(int k) { return k + (k >> 4); }

constexpr double FXP = 4294967296.0;   // Q32.32 fixed-point scale

// Round-7 structure (proven 19.6us) + two micro-opts:
//  (a) the 16 streaming float4 loads are issued BEFORE the metadata loads,
//      so the row stream starts at cycle 0;
//  (b) per-block results are accumulated with RELAXED integer atomicAdds in
//      Q32.32 fixed point (associative -> bit-deterministic; plain atomicAdd
//      emits no L2 writeback/invalidate — rounds 6/8/10 died on the ORDERING
//      semantics of agent-scope release/acquire, not the RMW itself).
// Finalize is then a 3-load single-thread kernel instead of a 16KB reduce.
__global__ __launch_bounds__(256, 4) void seg_loss_kernel(
    const float* __restrict__ rlogits,   // [B]
    const float* __restrict__ rlabels,   // [B]
    const float* __restrict__ logits,    // [B, T, 2]
    const int*   __restrict__ labels,    // [B, MS]
    const int*   __restrict__ bnd,       // [B, MS, 2]
    unsigned long long* __restrict__ acc) // [3]: nll_q32, cnt, bce_q32
{
    const int b    = blockIdx.x;
    const int tid  = threadIdx.x;
    const int lane = tid & 63;
    const int wave = tid >> 6;
    const float* row = logits + (size_t)b * T * 2;

    __shared__ float2 E2[NF4 + (NF4 >> 4) + 2];   // ~34.9 KB
    __shared__ float  wtot0[4], wtot1[4];
    __shared__ float  rn[4], rc[4];

    // ---- Phase 1a: issue all 16 streaming loads FIRST ----
    float4 v[16];
    {
        const float4* p = reinterpret_cast<const float4*>(row) + (size_t)tid * 16;
        #pragma unroll
        for (int j = 0; j < 16; ++j) v[j] = p[j];
    }

    // ---- Phase 0: metadata (overlaps with in-flight stream loads) ----
    int s_ = -1, e_ = -1, lab_ = 0;
    if (tid < MS) {
        const size_t bm = (size_t)b * MS + tid;
        s_   = bnd[bm * 2 + 0];
        e_   = bnd[bm * 2 + 1];
        lab_ = labels[bm];
    }
    float bce_b = 0.f;
    if (tid == 0) {
        const float x = rlogits[b];
        const float y = rlabels[b];
        const float t = log1pf(expf(-fabsf(x)));
        bce_b = y * (fmaxf(-x, 0.f) + t) + (1.f - y) * (fmaxf(x, 0.f) + t);
    }

    // ---- Phase 1b: chunk totals ----
    float ex0 = 0.f, ex1 = 0.f;
    #pragma unroll
    for (int j = 0; j < 16; ++j) {
        ex0 += v[j].x + v[j].z;
        ex1 += v[j].y + v[j].w;
    }

    // ---- Phase 2: scan of thread totals -> exclusive base; fill E2 ----
    float x0 = ex0, x1 = ex1;
    #pragma unroll
    for (int off = 1; off < 64; off <<= 1) {
        float y0 = __shfl_up(x0, off, 64);
        float y1 = __shfl_up(x1, off, 64);
        if (lane >= off) { x0 += y0; x1 += y1; }
    }
    if (lane == 63) { wtot0[wave] = x0; wtot1[wave] = x1; }
    __syncthreads();
    float pre0 = 0.f, pre1 = 0.f;
    #pragma unroll
    for (int w = 0; w < 3; ++w) {
        if (wave > w) { pre0 += wtot0[w]; pre1 += wtot1[w]; }
    }
    const float incl0 = x0 + pre0, incl1 = x1 + pre1;
    float run0 = incl0 - ex0, run1 = incl1 - ex1;   // exclusive base
    #pragma unroll
    for (int j = 0; j < 16; ++j) {                  // entry k = prefix before float4 k
        E2[17 * tid + j] = make_float2(run0, run1);
        run0 += v[j].x + v[j].z;
        run1 += v[j].y + v[j].w;
    }
    if (tid == 255) E2[pidx(NF4)] = make_float2(run0, run1);  // k = 4096
    __syncthreads();

    // ---- Phase 3: per-segment NLL (parallel over 128 segments) ----
    float nll = 0.f, cnt = 0.f;
    if (tid < MS && s_ != -1) {
        const int sc = min(max(s_, 0), T);
        const int ec = min(max(e_, 0), T);
        const int cs = sc >> 1;
        const int ce = ec >> 1;

        const float2 Ps = E2[pidx(cs)];
        const float2 Pe = E2[pidx(ce)];
        float q0 = Pe.x - Ps.x;
        float q1 = Pe.y - Ps.y;
        if (sc & 1) {  // subtract element sc-1
            float2 u = *reinterpret_cast<const float2*>(row + (size_t)(sc - 1) * 2);
            q0 -= u.x; q1 -= u.y;
        }
        if (ec & 1) {  // add element ec-1
            float2 u = *reinterpret_cast<const float2*>(row + (size_t)(ec - 1) * 2);
            q0 += u.x; q1 += u.y;
        }

        const int len = ec - sc;
        float p0 = 0.f, p1 = 0.f;
        if (len > 0) {
            const float inv = 1.0f / (float)len;
            p0 = q0 * inv;
            p1 = q1 * inv;
        }
        const float mx  = fmaxf(p0, p1);
        const float lse = mx + logf(expf(p0 - mx) + expf(p1 - mx));
        nll = lse - ((lab_ == 0) ? p0 : p1);
        cnt = 1.0f;
    }

    // ---- Phase 4: block reduce; tid 0 publishes via relaxed int atomics ----
    #pragma unroll
    for (int off = 32; off > 0; off >>= 1) {
        nll += __shfl_down(nll, off, 64);
        cnt += __shfl_down(cnt, off, 64);
    }
    if (lane == 0) { rn[wave] = nll; rc[wave] = cnt; }
    __syncthreads();
    if (tid == 0) {
        const float tn = rn[0] + rn[1] + rn[2] + rn[3];
        const float tc = rc[0] + rc[1] + rc[2] + rc[3];
        // Q32.32 fixed point: integer adds are associative -> deterministic.
        const long long qn = (long long)((double)tn * FXP +
                                         ((double)tn >= 0.0 ? 0.5 : -0.5));
        const long long qb = (long long)((double)bce_b * FXP + 0.5);
        atomicAdd(&acc[0], (unsigned long long)qn);
        atomicAdd(&acc[1], (unsigned long long)(long long)tc);
        atomicAdd(&acc[2], (unsigned long long)qb);
    }
}

// Trivial finalize: 3 loads, one thread.
__global__ void finalize_kernel(const unsigned long long* __restrict__ acc,
                                float* __restrict__ out)
{
    if (threadIdx.x == 0) {
        const double nll = (double)(long long)acc[0] / FXP;
        const double cnt = (double)(long long)acc[1];
        const double bce = (double)(long long)acc[2] / FXP;
        const double rank  = bce / (double)B;
        const double prune = (cnt > 0.0) ? (nll / cnt) : 0.0;
        out[0] = (float)(rank + 0.5 * prune);
    }
}

extern "C" void kernel_launch(void* const* d_in, const int* in_sizes, int n_in,
                              void* d_out, int out_size, void* d_ws, size_t ws_size,
                              hipStream_t stream) {
    const float* rlogits = (const float*)d_in[0];  // ranking_logits [B]
    const float* rlabels = (const float*)d_in[1];  // ranking_labels [B]
    const float* plogits = (const float*)d_in[2];  // pruning_logits [B,T,C]
    const int*   plabels = (const int*)  d_in[3];  // pruning_labels [B,MS]
    const int*   bnd     = (const int*)  d_in[4];  // boundaries [B,MS,2]

    float* out = (float*)d_out;
    unsigned long long* acc = (unsigned long long*)d_ws;   // 3 u64 accumulators

    // Accumulators must be 0 at kernel start on every call (first call sees
    // poisoned d_ws; replays must not inherit state).
    hipMemsetAsync(acc, 0, 3 * sizeof(unsigned long long), stream);

    seg_loss_kernel<<<B, 256, 0, stream>>>(rlogits, rlabels, plogits,
                                           plabels, bnd, acc);
    finalize_kernel<<<1, 64, 0, stream>>>(acc, out);
}

// Round 12
// 19.773 us; speedup vs baseline: 3.0553x; 3.0553x over previous
//
#include <hip/hip_runtime.h>

constexpr int B   = 1024;
constexpr int T   = 8192;
constexpr int MS  = 128;
constexpr int NF4 = T / 2;     // 4096 2-t prefix entries per row

// Padded LDS index for prefix entry k (k in [0, 4096]): idx = k + (k>>4).
// For k = 16*tid + j (j<16) this is 17*tid + j.
__device__ __forceinline__ int pidx(int k) { return k + (k >> 4); }

// PROVEN-BEST structure (round 7, 19.64us). Hard-won lessons baked in:
//  - NO cross-block communication inside this kernel. All four variants
//    (threadfence, ACQ_REL ticket, release-only ticket, plain relaxed
//    atomicAdd) regressed 2-6x: any cross-XCD ordering/RMW at 1024-block
//    scale stalls the L2s / fabric (R6/R8/R10/R11).
//  - __launch_bounds__(256,4) + no exv[] array: keeps the 16-float4 batch
//    unspilled (R6 post-mortem: default allocation serialized the loads).
//  - Occupancy (R9), coalesced+LDS-transpose loads (R3), and byte-skip
//    (R9) are all proven NEUTRAL — do not re-try.
// Phase 1: thread tid loads its contiguous 32-t chunk (16 float4), sums it.
// Phase 2: in-wave __shfl_up scan + cross-wave fixup -> 2-t-granularity
//          exclusive prefix E2[0..4096] in LDS.
// Phase 3: segment sum = E2[e>>1] - E2[s>>1] with <=2 element fixups.
// Phase 4: block reduce -> partial[b] = (nll, cnt, bce_b, 0)  (plain store).
__global__ __launch_bounds__(256, 4) void seg_loss_kernel(
    const float* __restrict__ rlogits,   // [B]
    const float* __restrict__ rlabels,   // [B]
    const float* __restrict__ logits,    // [B, T, 2]
    const int*   __restrict__ labels,    // [B, MS]
    const int*   __restrict__ bnd,       // [B, MS, 2]
    float4*      __restrict__ partial)   // [B] (nll, cnt, bce, 0)
{
    const int b    = blockIdx.x;
    const int tid  = threadIdx.x;
    const int lane = tid & 63;
    const int wave = tid >> 6;
    const float* row = logits + (size_t)b * T * 2;

    __shared__ float2 E2[NF4 + (NF4 >> 4) + 2];   // ~34.9 KB
    __shared__ float  wtot0[4], wtot1[4];
    __shared__ float  rn[4], rc[4];

    // ---- Phase 0: metadata; thread 0 computes this row's BCE term ----
    int s_ = -1, e_ = -1, lab_ = 0;
    if (tid < MS) {
        const size_t bm = (size_t)b * MS + tid;
        s_   = bnd[bm * 2 + 0];
        e_   = bnd[bm * 2 + 1];
        lab_ = labels[bm];
    }
    float bce_b = 0.f;
    if (tid == 0) {
        const float x = rlogits[b];
        const float y = rlabels[b];
        const float t = log1pf(expf(-fabsf(x)));
        bce_b = y * (fmaxf(-x, 0.f) + t) + (1.f - y) * (fmaxf(x, 0.f) + t);
    }

    // ---- Phase 1: batch-load chunk (16 float4 in flight), then sum ----
    float4 v[16];
    {
        const float4* p = reinterpret_cast<const float4*>(row) + (size_t)tid * 16;
        #pragma unroll
        for (int j = 0; j < 16; ++j) v[j] = p[j];
    }
    __builtin_amdgcn_sched_barrier(0);   // all 16 loads issued before compute
    float ex0 = 0.f, ex1 = 0.f;
    #pragma unroll
    for (int j = 0; j < 16; ++j) {
        ex0 += v[j].x + v[j].z;
        ex1 += v[j].y + v[j].w;
    }

    // ---- Phase 2: scan of thread totals -> exclusive base; fill E2 ----
    float x0 = ex0, x1 = ex1;
    #pragma unroll
    for (int off = 1; off < 64; off <<= 1) {
        float y0 = __shfl_up(x0, off, 64);
        float y1 = __shfl_up(x1, off, 64);
        if (lane >= off) { x0 += y0; x1 += y1; }
    }
    if (lane == 63) { wtot0[wave] = x0; wtot1[wave] = x1; }
    __syncthreads();
    float pre0 = 0.f, pre1 = 0.f;
    #pragma unroll
    for (int w = 0; w < 3; ++w) {
        if (wave > w) { pre0 += wtot0[w]; pre1 += wtot1[w]; }
    }
    const float incl0 = x0 + pre0,    incl1 = x1 + pre1;
    float run0 = incl0 - ex0, run1 = incl1 - ex1;   // exclusive base
    #pragma unroll
    for (int j = 0; j < 16; ++j) {                  // recompute prefix from v[]
        E2[17 * tid + j] = make_float2(run0, run1);
        run0 += v[j].x + v[j].z;
        run1 += v[j].y + v[j].w;
    }
    if (tid == 255) E2[pidx(NF4)] = make_float2(run0, run1);  // k = 4096
    __syncthreads();

    // ---- Phase 3: per-segment NLL (parallel over 128 segments) ----
    float nll = 0.f, cnt = 0.f;
    if (tid < MS && s_ != -1) {
        const int sc = min(max(s_, 0), T);
        const int ec = min(max(e_, 0), T);
        const int cs = sc >> 1;
        const int ce = ec >> 1;

        const float2 Ps = E2[pidx(cs)];
        const float2 Pe = E2[pidx(ce)];
        float q0 = Pe.x - Ps.x;
        float q1 = Pe.y - Ps.y;
        if (sc & 1) {  // subtract element sc-1
            float2 u = *reinterpret_cast<const float2*>(row + (size_t)(sc - 1) * 2);
            q0 -= u.x; q1 -= u.y;
        }
        if (ec & 1) {  // add element ec-1
            float2 u = *reinterpret_cast<const float2*>(row + (size_t)(ec - 1) * 2);
            q0 += u.x; q1 += u.y;
        }

        const int len = ec - sc;
        float p0 = 0.f, p1 = 0.f;
        if (len > 0) {
            const float inv = 1.0f / (float)len;
            p0 = q0 * inv;
            p1 = q1 * inv;
        }
        const float mx  = fmaxf(p0, p1);
        const float lse = mx + logf(expf(p0 - mx) + expf(p1 - mx));
        nll = lse - ((lab_ == 0) ? p0 : p1);
        cnt = 1.0f;
    }

    // ---- Phase 4: block reduce -> partial[b] (plain private store) ----
    #pragma unroll
    for (int off = 32; off > 0; off >>= 1) {
        nll += __shfl_down(nll, off, 64);
        cnt += __shfl_down(cnt, off, 64);
    }
    if (lane == 0) { rn[wave] = nll; rc[wave] = cnt; }
    __syncthreads();
    if (tid == 0) {
        partial[b] = make_float4(rn[0] + rn[1] + rn[2] + rn[3],
                                 rc[0] + rc[1] + rc[2] + rc[3],
                                 bce_b, 0.f);
    }
}

// Single-block finalize: reduce per-row partials (nll, cnt, bce) -> scalar.
__global__ __launch_bounds__(256) void finalize_kernel(
    const float4* __restrict__ partial,  // [B]
    float*        __restrict__ out)      // [1]
{
    const int tid  = threadIdx.x;
    const int lane = tid & 63;
    const int wave = tid >> 6;

    float nll = 0.f, cnt = 0.f, bce = 0.f;
    #pragma unroll
    for (int i = 0; i < 4; ++i) {
        const float4 p = partial[tid + i * 256];
        nll += p.x; cnt += p.y; bce += p.z;
    }

    #pragma unroll
    for (int off = 32; off > 0; off >>= 1) {
        nll += __shfl_down(nll, off, 64);
        cnt += __shfl_down(cnt, off, 64);
        bce += __shfl_down(bce, off, 64);
    }
    __shared__ float sn[4], sc[4], sb[4];
    if (lane == 0) { sn[wave] = nll; sc[wave] = cnt; sb[wave] = bce; }
    __syncthreads();
    if (tid == 0) {
        const float tn = sn[0] + sn[1] + sn[2] + sn[3];
        const float tc = sc[0] + sc[1] + sc[2] + sc[3];
        const float tb = sb[0] + sb[1] + sb[2] + sb[3];
        const float rank  = tb / (float)B;
        const float prune = (tc > 0.f) ? (tn / tc) : 0.f;
        out[0] = 1.0f * rank + 0.5f * prune;
    }
}

extern "C" void kernel_launch(void* const* d_in, const int* in_sizes, int n_in,
                              void* d_out, int out_size, void* d_ws, size_t ws_size,
                              hipStream_t stream) {
    const float* rlogits = (const float*)d_in[0];  // ranking_logits [B]
    const float* rlabels = (const float*)d_in[1];  // ranking_labels [B]
    const float* plogits = (const float*)d_in[2];  // pruning_logits [B,T,C]
    const int*   plabels = (const int*)  d_in[3];  // pruning_labels [B,MS]
    const int*   bnd     = (const int*)  d_in[4];  // boundaries [B,MS,2]

    float*  out     = (float*)d_out;
    float4* partial = (float4*)d_ws;   // B float4s, fully written by kernel 1

    seg_loss_kernel<<<B, 256, 0, stream>>>(rlogits, rlabels, plogits,
                                           plabels, bnd, partial);
    finalize_kernel<<<1, 256, 0, stream>>>(partial, out);
}